// Round 9
// baseline (649.994 us; speedup 1.0000x reference)
//
#include <hip/hip_runtime.h>
#include <hip/hip_bf16.h>

#define NTOT 8192
#define DDIM 256
#define JSPLIT 8
#define JCHUNK (NTOT / JSPLIT)   // 1024 j per wave
#define NBODY (JCHUNK / 16)      // 64 bodies (K=16)
#define JBSTR 520                // hTf2 nb-stride in frags (pad breaks 512KB alias)

typedef __attribute__((ext_vector_type(8)))  short short8;
typedef __attribute__((ext_vector_type(16))) float floatx16;

// ------- per-row scores + exp tables: rc=(e^s1, e^.01s1, e^-s1), etab=(e^s2, e^.01s2)
__global__ __launch_bounds__(256) void gat_scores(const float* __restrict__ h,
                                                  const float* __restrict__ a,
                                                  float4* __restrict__ rc,
                                                  float2* __restrict__ etab) {
  int row  = blockIdx.x * 4 + (threadIdx.x >> 6);
  int lane = threadIdx.x & 63;
  const float* hr = h + (size_t)row * DDIM;
  float p1 = 0.f, p2 = 0.f;
#pragma unroll
  for (int k = 0; k < DDIM / 64; ++k) {
    int idx  = lane + 64 * k;
    float hv = hr[idx];
    p1 += hv * a[idx];
    p2 += hv * a[DDIM + idx];
  }
#pragma unroll
  for (int off = 32; off > 0; off >>= 1) {
    p1 += __shfl_down(p1, off, 64);
    p2 += __shfl_down(p2, off, 64);
  }
  if (lane == 0) {
    rc[row]   = make_float4(__expf(p1), __expf(0.01f * p1), __expf(-p1), 0.f);
    etab[row] = make_float2(__expf(p2), __expf(0.01f * p2));
  }
}

// ---------------- pack adj -> word-major bitmask bitsT[jw][row] (R5-proven) --
__global__ __launch_bounds__(256) void gat_pack(const int* __restrict__ adj,
                                                unsigned* __restrict__ bitsT) {
  __shared__ unsigned words[64][65];
  const int t    = threadIdx.x;
  const int lane = t & 63;
  const int w    = t >> 6;
  const int r0   = blockIdx.x * 64;
  const int jb   = blockIdx.y * 2048;

#pragma unroll 2
  for (int rr = 0; rr < 16; ++rr) {
    const int rl = w * 16 + rr;
    const int* ap = adj + (size_t)(r0 + rl) * NTOT + jb + lane * 4;
#pragma unroll
    for (int R = 0; R < 8; ++R) {
      int4 v = *(const int4*)(ap + R * 256);
      unsigned nib = (v.x > 0 ? 1u : 0u) | (v.y > 0 ? 2u : 0u) |
                     (v.z > 0 ? 4u : 0u) | (v.w > 0 ? 8u : 0u);
      unsigned b8  = nib | (__shfl_xor((int)nib, 1, 64) << 4);
      unsigned b16 = b8  | (__shfl_xor((int)b8,  2, 64) << 8);
      unsigned b32 = b16 | (__shfl_xor((int)b16, 4, 64) << 16);
      if ((lane & 7) == 0) words[rl][R * 8 + (lane >> 3)] = b32;
    }
  }
  __syncthreads();

#pragma unroll 4
  for (int kk = 0; kk < 16; ++kk) {
    const int jwl = w * 16 + kk;
    bitsT[(size_t)(jb / 32 + jwl) * NTOT + r0 + lane] = words[lane][jwl];
  }
}

// ---------------- pack h -> 32x32x16 B-fragment-major bf16 (R8-proven) ------
__global__ __launch_bounds__(256) void gat_hpack(const float* __restrict__ h,
                                                 ushort* __restrict__ hTf2) {
  __shared__ float tile[64][257];
  const int t    = threadIdx.x;
  const int lane = t & 63;
  const int w    = t >> 6;
  const int half = lane >> 5;
  const int l31  = lane & 31;
  const int j0   = blockIdx.x * 64;

#pragma unroll
  for (int it = 0; it < 16; ++it) {
    int r = it * 4 + w;
    float4 v = *(const float4*)(h + (size_t)(j0 + r) * DDIM + lane * 4);
    tile[r][lane * 4 + 0] = v.x; tile[r][lane * 4 + 1] = v.y;
    tile[r][lane * 4 + 2] = v.z; tile[r][lane * 4 + 3] = v.w;
  }
  __syncthreads();

  const int jb = blockIdx.x * 4 + w;
#pragma unroll
  for (int nb = 0; nb < 8; ++nb) {
    short8 vv;
#pragma unroll
    for (int i = 0; i < 8; ++i) {
      float f = tile[w * 16 + half * 8 + i][nb * 32 + l31];
      __hip_bfloat16 b = __float2bfloat16(f);
      vv[i] = *(short*)&b;
    }
    *(short8*)(hTf2 + ((size_t)nb * JBSTR + jb) * 512 + lane * 8) = vv;
  }
}

// ---------------- fused mask+softmax+P@h, rt=4 x nb=2, barrier-free ---------
// 512 blocks x 256 thr; wave wg: rows [rg*128,+128), cols [cg*64,+64),
// j in [js*1024,+1024). B traffic 4x lower than R8; adj via bitsT only.
__global__ __launch_bounds__(256, 2) void gat_attn(const ushort* __restrict__ hTf2,
                                                   const unsigned* __restrict__ bitsT,
                                                   const float4* __restrict__ rc,
                                                   const float* __restrict__ etabf,
                                                   float* __restrict__ part,
                                                   float* __restrict__ lpart) {
  const int t    = threadIdx.x;
  const int lane = t & 63;
  const int w    = t >> 6;
  const int half = lane >> 5;
  const int l31  = lane & 31;
  const int wg   = blockIdx.x * 4 + w;
  const int js   = wg & 7;
  const int cg   = (wg >> 3) & 3;
  const int rg   = wg >> 5;
  const int rbase = rg * 128;
  const int jbase = js * JCHUNK;
  const int jb32  = jbase / 32;    // bitmask group base
  const int jb16  = jbase / 16;    // B-frag base

  float E1[4], E2[4], Tt[4];
#pragma unroll
  for (int t4 = 0; t4 < 4; ++t4) {
    float4 v = rc[rbase + 32 * t4 + l31];
    E1[t4] = v.x; E2[t4] = v.y; Tt[t4] = v.z;
  }

  const unsigned* btp = bitsT + (size_t)jb32 * NTOT + rbase + l31;
  const float*    etp = etabf + 2 * (jbase + half * 8);
  const ushort*   bfp = hTf2 + ((size_t)(2 * cg) * JBSTR + jb16) * 512 + lane * 8;

  floatx16 acc[4][2];
#pragma unroll
  for (int t4 = 0; t4 < 4; ++t4)
#pragma unroll
    for (int q = 0; q < 2; ++q)
#pragma unroll
      for (int r = 0; r < 16; ++r) acc[t4][q][r] = 0.f;
  float lp[4] = {0.f, 0.f, 0.f, 0.f};

  // depth-2 parity rings: etab + B-frags; bitmask words per 2-body group
  float4 eR[2][4];
  short8 bR[2][2];
#pragma unroll
  for (int P = 0; P < 2; ++P) {
#pragma unroll
    for (int k = 0; k < 4; ++k)
      eR[P][k] = ((const float4*)(etp + P * 32))[k];
#pragma unroll
    for (int q = 0; q < 2; ++q)
      bR[P][q] = *(const short8*)(bfp + ((size_t)q * JBSTR + P) * 512);
  }
  unsigned W[4];
#pragma unroll
  for (int t4 = 0; t4 < 4; ++t4) W[t4] = btp[32 * t4];

#define BODY(JT, P, P16)                                                       \
  {                                                                            \
    short8 pa[4];                                                              \
    _Pragma("unroll")                                                          \
    for (int t4 = 0; t4 < 4; ++t4) {                                           \
      const unsigned bm = (W[t4] >> ((P16) + half * 8)) & 0xffu;               \
      _Pragma("unroll")                                                        \
      for (int i = 0; i < 8; ++i) {                                            \
        const float t1v = eR[P][i >> 1][(i & 1) ? 2 : 0];                      \
        const float t2v = eR[P][i >> 1][(i & 1) ? 3 : 1];                      \
        float v = (t1v > Tt[t4]) ? E1[t4] * t1v : E2[t4] * t2v;                \
        v = ((bm >> i) & 1u) ? v : 0.f;                                        \
        lp[t4] += v;                                                           \
        __hip_bfloat16 b = __float2bfloat16(v);                                \
        pa[t4][i] = *(short*)&b;                                               \
      }                                                                        \
    }                                                                          \
    short8 b0 = bR[P][0], b1 = bR[P][1];                                       \
    if ((JT) + 2 < NBODY) {                                                    \
      const float* en = etp + ((JT) + 2) * 32;                                 \
      _Pragma("unroll")                                                        \
      for (int k = 0; k < 4; ++k) eR[P][k] = ((const float4*)en)[k];           \
      _Pragma("unroll")                                                        \
      for (int q = 0; q < 2; ++q)                                              \
        bR[P][q] = *(const short8*)(bfp + ((size_t)q * JBSTR + (JT) + 2) * 512); \
    }                                                                          \
    _Pragma("unroll")                                                          \
    for (int t4 = 0; t4 < 4; ++t4) {                                           \
      acc[t4][0] = __builtin_amdgcn_mfma_f32_32x32x16_bf16(pa[t4], b0, acc[t4][0], 0, 0, 0); \
      acc[t4][1] = __builtin_amdgcn_mfma_f32_32x32x16_bf16(pa[t4], b1, acc[t4][1], 0, 0, 0); \
    }                                                                          \
  }

  for (int g = 0; g < 32; ++g) {
    unsigned Wn[4];
    if (g + 1 < 32) {
#pragma unroll
      for (int t4 = 0; t4 < 4; ++t4)
        Wn[t4] = btp[(size_t)(g + 1) * NTOT + 32 * t4];
    }
    const int jt = 2 * g;
    BODY(jt, 0, 0)
    BODY(jt + 1, 1, 16)
#pragma unroll
    for (int t4 = 0; t4 < 4; ++t4) W[t4] = Wn[t4];
  }
#undef BODY

  // ---- row sums (lanes l and l^32 share a row); cg==0 writes ----
#pragma unroll
  for (int t4 = 0; t4 < 4; ++t4) lp[t4] += __shfl_xor(lp[t4], 32, 64);
  if (cg == 0 && lane < 32) {
#pragma unroll
    for (int t4 = 0; t4 < 4; ++t4)
      lpart[(size_t)js * NTOT + rbase + 32 * t4 + lane] = lp[t4];
  }

  // ---- partial store: C/D layout col=lane&31, row=(reg&3)+8*(reg>>2)+4*half
  float* pp = part + ((size_t)js * NTOT + rbase) * DDIM + cg * 64;
#pragma unroll
  for (int t4 = 0; t4 < 4; ++t4)
#pragma unroll
    for (int q = 0; q < 2; ++q)
#pragma unroll
      for (int reg = 0; reg < 16; ++reg) {
        int rloc = (reg & 3) + 8 * (reg >> 2) + 4 * half;
        pp[(size_t)(32 * t4 + rloc) * DDIM + q * 32 + l31] = acc[t4][q][reg];
      }
}

// ---------------- reduce j-split partials + softmax divide ------------------
__global__ __launch_bounds__(256) void gat_reduce(const float* __restrict__ part,
                                                  const float* __restrict__ lpart,
                                                  float* __restrict__ out) {
  const int row = blockIdx.x;
  const int t   = threadIdx.x;
  float l = 0.f;
#pragma unroll
  for (int js = 0; js < JSPLIT; ++js) l += lpart[(size_t)js * NTOT + row];
  float s = 0.f;
#pragma unroll
  for (int js = 0; js < JSPLIT; ++js)
    s += part[((size_t)js * NTOT + row) * DDIM + t];
  out[(size_t)row * DDIM + t] = s / l;
}

extern "C" void kernel_launch(void* const* d_in, const int* in_sizes, int n_in,
                              void* d_out, int out_size, void* d_ws, size_t ws_size,
                              hipStream_t stream) {
  const float* h   = (const float*)d_in[0];
  const int*   adj = (const int*)d_in[1];
  const float* a   = (const float*)d_in[2];
  float* out = (float*)d_out;
  char* ws = (char*)d_ws;

  float4*   rc    = (float4*)(ws);               // 128 KB @ 0
  float2*   etab  = (float2*)(ws + (256 << 10)); // 64 KB  @ 256K
  unsigned* bitsT = (unsigned*)(ws + (1 << 20)); // 8 MB   @ 1M
  ushort*   hTf2  = (ushort*)(ws + (10 << 20));  // ~4.2MB @ 10M
  float*    part  = (float*)(ws + (16 << 20));   // 64 MB  @ 16M
  float*    lpart = (float*)(ws + (82 << 20));   // 256 KB @ 82M

  gat_scores<<<NTOT / 4, 256, 0, stream>>>(h, a, rc, etab);
  gat_pack<<<dim3(NTOT / 64, 4), 256, 0, stream>>>(adj, bitsT);
  gat_hpack<<<NTOT / 64, 256, 0, stream>>>(h, hTf2);
  gat_attn<<<512, 256, 0, stream>>>(hTf2, bitsT, rc, (const float*)etab, part, lpart);
  gat_reduce<<<NTOT, 256, 0, stream>>>(part, lpart, out);
}

// Round 10
// 511.294 us; speedup vs baseline: 1.2713x; 1.2713x over previous
//
#include <hip/hip_runtime.h>
#include <hip/hip_bf16.h>

#define NTOT 8192
#define DDIM 256
#define JSPLIT 4
#define JCHUNK (NTOT / JSPLIT)   // 2048 j per wave
#define NGRP (JCHUNK / 32)       // 64 groups of 2 bodies (K=16 each)
#define JBSTR 520                // hTf2 nb-stride in frags (pad breaks 512KB alias)

typedef __attribute__((ext_vector_type(8)))  short short8;
typedef __attribute__((ext_vector_type(16))) float floatx16;

// ---------------- per-row scores s1 = h@a[:D], s2 = h@a[D:] -----------------
__global__ __launch_bounds__(256) void gat_scores(const float* __restrict__ h,
                                                  const float* __restrict__ a,
                                                  float* __restrict__ s1,
                                                  float* __restrict__ s2) {
  int row  = blockIdx.x * 4 + (threadIdx.x >> 6);
  int lane = threadIdx.x & 63;
  const float* hr = h + (size_t)row * DDIM;
  float p1 = 0.f, p2 = 0.f;
#pragma unroll
  for (int k = 0; k < DDIM / 64; ++k) {
    int idx  = lane + 64 * k;
    float hv = hr[idx];
    p1 += hv * a[idx];
    p2 += hv * a[DDIM + idx];
  }
#pragma unroll
  for (int off = 32; off > 0; off >>= 1) {
    p1 += __shfl_down(p1, off, 64);
    p2 += __shfl_down(p2, off, 64);
  }
  if (lane == 0) { s1[row] = p1; s2[row] = p2; }
}

// ---------------- pack adj -> word-major bitmask bitsT[jw][row] (proven) ----
__global__ __launch_bounds__(256) void gat_pack(const int* __restrict__ adj,
                                                unsigned* __restrict__ bitsT) {
  __shared__ unsigned words[64][65];
  const int t    = threadIdx.x;
  const int lane = t & 63;
  const int w    = t >> 6;
  const int r0   = blockIdx.x * 64;
  const int jb   = blockIdx.y * 2048;

#pragma unroll 2
  for (int rr = 0; rr < 16; ++rr) {
    const int rl = w * 16 + rr;
    const int* ap = adj + (size_t)(r0 + rl) * NTOT + jb + lane * 4;
#pragma unroll
    for (int R = 0; R < 8; ++R) {
      int4 v = *(const int4*)(ap + R * 256);
      unsigned nib = (v.x > 0 ? 1u : 0u) | (v.y > 0 ? 2u : 0u) |
                     (v.z > 0 ? 4u : 0u) | (v.w > 0 ? 8u : 0u);
      unsigned b8  = nib | (__shfl_xor((int)nib, 1, 64) << 4);
      unsigned b16 = b8  | (__shfl_xor((int)b8,  2, 64) << 8);
      unsigned b32 = b16 | (__shfl_xor((int)b16, 4, 64) << 16);
      if ((lane & 7) == 0) words[rl][R * 8 + (lane >> 3)] = b32;
    }
  }
  __syncthreads();

#pragma unroll 4
  for (int kk = 0; kk < 16; ++kk) {
    const int jwl = w * 16 + kk;
    bitsT[(size_t)(jb / 32 + jwl) * NTOT + r0 + lane] = words[lane][jwl];
  }
}

// ---------------- pack h -> 32x32x16 B-fragment-major bf16 (proven) ---------
__global__ __launch_bounds__(256) void gat_hpack(const float* __restrict__ h,
                                                 ushort* __restrict__ hTf2) {
  __shared__ float tile[64][257];
  const int t    = threadIdx.x;
  const int lane = t & 63;
  const int w    = t >> 6;
  const int half = lane >> 5;
  const int l31  = lane & 31;
  const int j0   = blockIdx.x * 64;

#pragma unroll
  for (int it = 0; it < 16; ++it) {
    int r = it * 4 + w;
    float4 v = *(const float4*)(h + (size_t)(j0 + r) * DDIM + lane * 4);
    tile[r][lane * 4 + 0] = v.x; tile[r][lane * 4 + 1] = v.y;
    tile[r][lane * 4 + 2] = v.z; tile[r][lane * 4 + 3] = v.w;
  }
  __syncthreads();

  const int jb = blockIdx.x * 4 + w;
#pragma unroll
  for (int nb = 0; nb < 8; ++nb) {
    short8 vv;
#pragma unroll
    for (int i = 0; i < 8; ++i) {
      float f = tile[w * 16 + half * 8 + i][nb * 32 + l31];
      __hip_bfloat16 b = __float2bfloat16(f);
      vv[i] = *(short*)&b;
    }
    *(short8*)(hTf2 + ((size_t)nb * JBSTR + jb) * 512 + lane * 8) = vv;
  }
}

// ---------------- fused mask+softmax+P@h: small waves, 4/SIMD, XCD-pinned ---
// 1024 blocks x 256 thr. slot=bx&7 (~XCD): js=slot&3 (j-chunk pinned per XCD),
// rowtile=(bx>>3)*2+(slot>>2). Wave cg: cols [cg*64,+64). Lane owns ONE row.
// acc=32 AGPR only; batch depth-1 loads; TLP (4 waves/SIMD) hides latency.
__global__ __launch_bounds__(256, 4) void gat_attn(const ushort* __restrict__ hTf2,
                                                   const unsigned* __restrict__ bitsT,
                                                   const float* __restrict__ s1g,
                                                   const float* __restrict__ s2g,
                                                   float* __restrict__ part,
                                                   float* __restrict__ lpart) {
  const int t    = threadIdx.x;
  const int lane = t & 63;
  const int cg   = t >> 6;
  const int half = lane >> 5;
  const int l31  = lane & 31;
  const int bx   = blockIdx.x;
  const int slot = bx & 7;
  const int js   = slot & 3;
  const int rowtile = (bx >> 3) * 2 + (slot >> 2);
  const int rbase = rowtile * 32;
  const int row   = rbase + l31;
  const int jbase = js * JCHUNK;

  const float s1v = s1g[row];
  const unsigned* btp = bitsT + (size_t)(jbase / 32) * NTOT + row;
  const float*    s2p = s2g + jbase + half * 8;
  const ushort*   bfp = hTf2 + ((size_t)(2 * cg) * JBSTR + jbase / 16) * 512 + lane * 8;

  floatx16 acc0, acc1;
#pragma unroll
  for (int r = 0; r < 16; ++r) { acc0[r] = 0.f; acc1[r] = 0.f; }
  float lp = 0.f;

  for (int g = 0; g < NGRP; ++g) {
    // ---- batch loads for this group (2 bodies): 1 dword + 4 float4 + 4 short8
    const unsigned W = btp[(size_t)g * NTOT];
    const float* sp = s2p + g * 32;
    const float4 sA = ((const float4*)sp)[0];
    const float4 sB = ((const float4*)(sp + 4))[0];
    const float4 sC = ((const float4*)(sp + 16))[0];
    const float4 sD = ((const float4*)(sp + 20))[0];
    const ushort* bp = bfp + (size_t)(2 * g) * 512;
    const short8 b00 = *(const short8*)(bp);
    const short8 b01 = *(const short8*)(bp + (size_t)JBSTR * 512);
    const short8 b10 = *(const short8*)(bp + 512);
    const short8 b11 = *(const short8*)(bp + (size_t)JBSTR * 512 + 512);

    short8 pa;
#define PK(i, sv)                                                        \
    {                                                                    \
      float m = s1v + (sv);                                              \
      float e = fmaxf(m, 0.01f * m);                                     \
      float p = ((bm >> (i)) & 1u) ? __expf(e) : 0.f;                    \
      lp += p;                                                           \
      __hip_bfloat16 b = __float2bfloat16(p);                            \
      pa[i] = *(short*)&b;                                               \
    }
    // ---- body 0 ----
    {
      const unsigned bm = (W >> (half * 8)) & 0xffu;
      PK(0, sA.x) PK(1, sA.y) PK(2, sA.z) PK(3, sA.w)
      PK(4, sB.x) PK(5, sB.y) PK(6, sB.z) PK(7, sB.w)
      acc0 = __builtin_amdgcn_mfma_f32_32x32x16_bf16(pa, b00, acc0, 0, 0, 0);
      acc1 = __builtin_amdgcn_mfma_f32_32x32x16_bf16(pa, b01, acc1, 0, 0, 0);
    }
    // ---- body 1 ----
    {
      const unsigned bm = (W >> (16 + half * 8)) & 0xffu;
      PK(0, sC.x) PK(1, sC.y) PK(2, sC.z) PK(3, sC.w)
      PK(4, sD.x) PK(5, sD.y) PK(6, sD.z) PK(7, sD.w)
      acc0 = __builtin_amdgcn_mfma_f32_32x32x16_bf16(pa, b10, acc0, 0, 0, 0);
      acc1 = __builtin_amdgcn_mfma_f32_32x32x16_bf16(pa, b11, acc1, 0, 0, 0);
    }
#undef PK
  }

  // ---- row sums (lanes l, l^32 share a row); identical across cg: cg0 writes
  lp += __shfl_xor(lp, 32, 64);
  if (cg == 0 && lane < 32) lpart[(size_t)js * NTOT + rbase + lane] = lp;

  // ---- partial store: C/D layout col=l31, row=(reg&3)+8*(reg>>2)+4*half ----
  float* pp = part + ((size_t)js * NTOT + rbase) * DDIM + cg * 64;
#pragma unroll
  for (int reg = 0; reg < 16; ++reg) {
    const int rloc = (reg & 3) + 8 * (reg >> 2) + 4 * half;
    pp[(size_t)rloc * DDIM + l31]      = acc0[reg];
    pp[(size_t)rloc * DDIM + 32 + l31] = acc1[reg];
  }
}

// ---------------- reduce j-split partials + softmax divide ------------------
__global__ __launch_bounds__(256) void gat_reduce(const float* __restrict__ part,
                                                  const float* __restrict__ lpart,
                                                  float* __restrict__ out) {
  const int row = blockIdx.x;
  const int t   = threadIdx.x;
  float l = 0.f;
#pragma unroll
  for (int js = 0; js < JSPLIT; ++js) l += lpart[(size_t)js * NTOT + row];
  float s = 0.f;
#pragma unroll
  for (int js = 0; js < JSPLIT; ++js)
    s += part[((size_t)js * NTOT + row) * DDIM + t];
  out[(size_t)row * DDIM + t] = s / l;
}

extern "C" void kernel_launch(void* const* d_in, const int* in_sizes, int n_in,
                              void* d_out, int out_size, void* d_ws, size_t ws_size,
                              hipStream_t stream) {
  const float* h   = (const float*)d_in[0];
  const int*   adj = (const int*)d_in[1];
  const float* a   = (const float*)d_in[2];
  float* out = (float*)d_out;
  char* ws = (char*)d_ws;

  float*    s1    = (float*)(ws);                // 32 KB @ 0
  float*    s2    = (float*)(ws + (64 << 10));   // 32 KB @ 64K
  unsigned* bitsT = (unsigned*)(ws + (1 << 20)); // 8 MB   @ 1M
  ushort*   hTf2  = (ushort*)(ws + (10 << 20));  // ~4.3MB @ 10M
  float*    part  = (float*)(ws + (16 << 20));   // 32 MB  @ 16M
  float*    lpart = (float*)(ws + (50 << 20));   // 128 KB @ 50M

  gat_scores<<<NTOT / 4, 256, 0, stream>>>(h, a, s1, s2);
  gat_pack<<<dim3(NTOT / 64, 4), 256, 0, stream>>>(adj, bitsT);
  gat_hpack<<<NTOT / 64, 256, 0, stream>>>(h, hTf2);
  gat_attn<<<1024, 256, 0, stream>>>(hTf2, bitsT, s1, s2, part, lpart);
  gat_reduce<<<NTOT, 256, 0, stream>>>(part, lpart, out);
}

// Round 11
// 469.526 us; speedup vs baseline: 1.3844x; 1.0890x over previous
//
#include <hip/hip_runtime.h>
#include <hip/hip_bf16.h>

#define NTOT 8192
#define DDIM 256
#define JSPLIT 4
#define JCHUNK (NTOT / JSPLIT)   // 2048 j per block
#define BK 128                   // j per chunk (staged P tile)
#define NCHUNK (JCHUNK / BK)     // 16
#define JBSTR 520                // hTf2 nb-stride in frags (pad breaks 512KB alias)

typedef __attribute__((ext_vector_type(8)))  short short8;
typedef __attribute__((ext_vector_type(16))) float floatx16;

// ---------------- per-row scores s1 = h@a[:D], s2 = h@a[D:] -----------------
__global__ __launch_bounds__(256) void gat_scores(const float* __restrict__ h,
                                                  const float* __restrict__ a,
                                                  float* __restrict__ s1,
                                                  float* __restrict__ s2) {
  int row  = blockIdx.x * 4 + (threadIdx.x >> 6);
  int lane = threadIdx.x & 63;
  const float* hr = h + (size_t)row * DDIM;
  float p1 = 0.f, p2 = 0.f;
#pragma unroll
  for (int k = 0; k < DDIM / 64; ++k) {
    int idx  = lane + 64 * k;
    float hv = hr[idx];
    p1 += hv * a[idx];
    p2 += hv * a[DDIM + idx];
  }
#pragma unroll
  for (int off = 32; off > 0; off >>= 1) {
    p1 += __shfl_down(p1, off, 64);
    p2 += __shfl_down(p2, off, 64);
  }
  if (lane == 0) { s1[row] = p1; s2[row] = p2; }
}

// ---------------- pack h -> 32x32x16 B-fragment-major bf16 (proven) ---------
__global__ __launch_bounds__(256) void gat_hpack(const float* __restrict__ h,
                                                 ushort* __restrict__ hTf2) {
  __shared__ float tile[64][257];
  const int t    = threadIdx.x;
  const int lane = t & 63;
  const int w    = t >> 6;
  const int half = lane >> 5;
  const int l31  = lane & 31;
  const int j0   = blockIdx.x * 64;

#pragma unroll
  for (int it = 0; it < 16; ++it) {
    int r = it * 4 + w;
    float4 v = *(const float4*)(h + (size_t)(j0 + r) * DDIM + lane * 4);
    tile[r][lane * 4 + 0] = v.x; tile[r][lane * 4 + 1] = v.y;
    tile[r][lane * 4 + 2] = v.z; tile[r][lane * 4 + 3] = v.w;
  }
  __syncthreads();

  const int jb = blockIdx.x * 4 + w;
#pragma unroll
  for (int nb = 0; nb < 8; ++nb) {
    short8 vv;
#pragma unroll
    for (int i = 0; i < 8; ++i) {
      float f = tile[w * 16 + half * 8 + i][nb * 32 + l31];
      __hip_bfloat16 b = __float2bfloat16(f);
      vv[i] = *(short*)&b;
    }
    *(short8*)(hTf2 + ((size_t)nb * JBSTR + jb) * 512 + lane * 8) = vv;
  }
}

// ---------------- canonical LDS-staged fused softmax + P@h ------------------
// 1024 blocks x 512 thr. Block: rows [rg*32,+32), cols all 256, j-chunk
// [js*2048,+2048) (js XCD-pinned via bx&7). Per BK=128 chunk: 512 threads
// build P(32x128 bf16) once into dbuf LDS (A-frag order); 8 col-waves (nb=w)
// consume via ds_read_b128 + 8 MFMAs. acc = 16 regs. adj read directly here.
__global__ __launch_bounds__(512, 4) void gat_attn(const ushort* __restrict__ hTf2,
                                                   const int*   __restrict__ adj,
                                                   const float* __restrict__ s1g,
                                                   const float* __restrict__ s2g,
                                                   float* __restrict__ part,
                                                   float* __restrict__ lpart) {
  __shared__ ushort pbuf[2][16 * 33 * 8];   // [parity][(jg*33 + row)*8 + i]
  __shared__ float  lred[32][17];

  const int t    = threadIdx.x;
  const int lane = t & 63;
  const int w    = t >> 6;           // wave 0..7 = col-group nb
  const int half = lane >> 5;
  const int l31  = lane & 31;
  const int bx   = blockIdx.x;
  const int slot = bx & 7;
  const int js   = slot >> 1;        // j-slice pinned per XCD-pair
  const int rg   = (bx >> 3) * 2 + (slot & 1);
  const int r0   = rg * 32;
  const int jbase = js * JCHUNK;

  // P-build role: row pr, 8-j segment seg
  const int pr  = t >> 4;            // 0..31
  const int seg = t & 15;            // 0..15 (seg*8 j within chunk)
  const int prow = r0 + pr;
  const float s1v = s1g[prow];

  const int*   adjp = adj + (size_t)prow * NTOT + jbase + seg * 8;
  const float* s2p  = s2g + jbase + seg * 8;
  const ushort* bfp = hTf2 + ((size_t)w * JBSTR + jbase / 16) * 512 + lane * 8;

  floatx16 acc;
#pragma unroll
  for (int r = 0; r < 16; ++r) acc[r] = 0.f;
  float lp = 0.f;

  // depth-2 rings, explicit parity registers (no dynamic indexing)
  int4   a0A = ((const int4*)adjp)[0],        a0B = ((const int4*)(adjp + 4))[0];
  int4   a1A = ((const int4*)(adjp + BK))[0], a1B = ((const int4*)(adjp + BK + 4))[0];
  float4 s0A = ((const float4*)s2p)[0],        s0B = ((const float4*)(s2p + 4))[0];
  float4 s1A = ((const float4*)(s2p + BK))[0], s1B = ((const float4*)(s2p + BK + 4))[0];

#define PK(i, mi, sv)                                                    \
  {                                                                      \
    float e = s1v + (sv);                                                \
    e = fmaxf(e, 0.01f * e);                                             \
    float p = ((mi) > 0) ? __expf(e) : 0.f;                              \
    lp += p;                                                             \
    __hip_bfloat16 b = __float2bfloat16(p);                              \
    pw[i] = *(short*)&b;                                                 \
  }

#define BODY(C, AA, AB, SA, SB, PAR)                                     \
  {                                                                      \
    /* B-frags for this chunk: 8 x 1KB contiguous (L2-resident slice) */ \
    short8 bfr[8];                                                       \
    _Pragma("unroll")                                                    \
    for (int kc = 0; kc < 8; ++kc)                                       \
      bfr[kc] = *(const short8*)(bfp + (size_t)((C) * 8 + kc) * 512);    \
    /* build P(C) -> pbuf[PAR] in A-frag order */                        \
    short8 pw;                                                           \
    PK(0, AA.x, SA.x) PK(1, AA.y, SA.y) PK(2, AA.z, SA.z) PK(3, AA.w, SA.w) \
    PK(4, AB.x, SB.x) PK(5, AB.y, SB.y) PK(6, AB.z, SB.z) PK(7, AB.w, SB.w) \
    *(short8*)&pbuf[PAR][(seg * 33 + pr) * 8] = pw;                      \
    /* refill ring for chunk C+2 */                                      \
    if ((C) + 2 < NCHUNK) {                                              \
      AA = ((const int4*)(adjp + ((C) + 2) * BK))[0];                    \
      AB = ((const int4*)(adjp + ((C) + 2) * BK + 4))[0];                \
      SA = ((const float4*)(s2p + ((C) + 2) * BK))[0];                   \
      SB = ((const float4*)(s2p + ((C) + 2) * BK + 4))[0];               \
    }                                                                    \
    __syncthreads();  /* P(C) visible; prev reads of pbuf[PAR] done */   \
    /* MFMA phase: 8 kc, A from LDS, B from regs */                      \
    _Pragma("unroll")                                                    \
    for (int kc = 0; kc < 8; ++kc) {                                     \
      const int jg = kc * 2 + half;                                      \
      short8 af = *(const short8*)&pbuf[PAR][(jg * 33 + l31) * 8];       \
      acc = __builtin_amdgcn_mfma_f32_32x32x16_bf16(af, bfr[kc], acc, 0, 0, 0); \
    }                                                                    \
  }

  for (int c = 0; c < NCHUNK; c += 2) {
    BODY(c,     a0A, a0B, s0A, s0B, 0)
    BODY(c + 1, a1A, a1B, s1A, s1B, 1)
  }
#undef BODY
#undef PK

  // ---- row-sum partials: lred[row][seg] -> lpart[js][row] ----
  lred[pr][seg] = lp;
  __syncthreads();
  if (t < 32) {
    float s = 0.f;
#pragma unroll
    for (int k = 0; k < 16; ++k) s += lred[t][k];
    lpart[(size_t)js * NTOT + r0 + t] = s;
  }

  // ---- partial store: C/D layout col=l31, row=(reg&3)+8*(reg>>2)+4*half ----
  float* pp = part + ((size_t)js * NTOT + r0) * DDIM + w * 32 + l31;
#pragma unroll
  for (int reg = 0; reg < 16; ++reg) {
    const int rloc = (reg & 3) + 8 * (reg >> 2) + 4 * half;
    pp[(size_t)rloc * DDIM] = acc[reg];
  }
}

// ---------------- reduce j-split partials + softmax divide ------------------
__global__ __launch_bounds__(256) void gat_reduce(const float* __restrict__ part,
                                                  const float* __restrict__ lpart,
                                                  float* __restrict__ out) {
  const int row = blockIdx.x;
  const int t   = threadIdx.x;
  float l = 0.f;
#pragma unroll
  for (int js = 0; js < JSPLIT; ++js) l += lpart[(size_t)js * NTOT + row];
  float s = 0.f;
#pragma unroll
  for (int js = 0; js < JSPLIT; ++js)
    s += part[((size_t)js * NTOT + row) * DDIM + t];
  out[(size_t)row * DDIM + t] = s / l;
}

extern "C" void kernel_launch(void* const* d_in, const int* in_sizes, int n_in,
                              void* d_out, int out_size, void* d_ws, size_t ws_size,
                              hipStream_t stream) {
  const float* h   = (const float*)d_in[0];
  const int*   adj = (const int*)d_in[1];
  const float* a   = (const float*)d_in[2];
  float* out = (float*)d_out;
  char* ws = (char*)d_ws;

  float*  s1    = (float*)(ws);                // 32 KB @ 0
  float*  s2    = (float*)(ws + (64 << 10));   // 32 KB @ 64K
  ushort* hTf2  = (ushort*)(ws + (1 << 20));   // ~4.3 MB @ 1M
  float*  part  = (float*)(ws + (8 << 20));    // 32 MB  @ 8M
  float*  lpart = (float*)(ws + (48 << 20));   // 128 KB @ 48M

  gat_scores<<<NTOT / 4, 256, 0, stream>>>(h, a, s1, s2);
  gat_hpack<<<NTOT / 64, 256, 0, stream>>>(h, hTf2);
  gat_attn<<<1024, 512, 0, stream>>>(hTf2, adj, s1, s2, part, lpart);
  gat_reduce<<<NTOT, 256, 0, stream>>>(part, lpart, out);
}